// Round 12
// baseline (305.023 us; speedup 1.0000x reference)
//
#include <hip/hip_runtime.h>
#include <stdint.h>

#define N_BATCH 128
#define C_IN    156
#define T_SMP   156
#define H_HID   1024
#define O_OUT   20

// Baked permutation (from reference _top_down construction)
__constant__ int PERM_C[156] = {
  20,21,48,49,68,69,6,7,34,35,58,59,12,13,2,3,38,39,72,73,56,57,22,23,16,17,
  64,65,44,45,30,31,0,1,10,11,28,29,40,41,52,53,66,67,76,77,46,47,32,33,18,19,
  60,61,74,75,54,55,26,27,4,5,42,43,62,63,14,15,36,37,70,71,8,9,24,25,50,51,
  98,99,126,127,146,147,84,85,112,113,136,137,90,91,80,81,116,117,150,151,134,135,
  100,101,94,95,142,143,122,123,108,109,78,79,88,89,106,107,118,119,130,131,144,145,
  154,155,124,125,110,111,96,97,138,139,152,153,132,133,104,105,82,83,120,121,
  140,141,92,93,114,115,148,149,86,87,102,103,128,129
};

// ref_next[d] = REF_KERNEL[d+1] = -20*(d+1)*exp(-d), correctly-rounded fp32
__device__ __constant__ float REFN_C[15] = {
  -20.0f,
  -14.7151776468576930f,
  -8.1201169941967630f,
  -3.9829654694291155f,
  -1.8315638888734178f,
  -0.80855363989025606f,
  -0.34702530473329017f,
  -0.14590111448872258f,
  -0.060383273022452135f,
  -0.024681960817335913f,
  -0.0099879845477466679f,
  -0.0040084081896589585f,
  -0.0015974952118653345f,
  -0.00063348115597555236f,
  -0.00024945861573107036f
};

#define IIR_A   0.904837418035959573    // exp(-1/10)
#define IIR_CK  0.271828182845904524    // e/10
// CK * 2^-23 folded into the i32->f64 scale (IIR is linear)
#define CKSCALE23 (IIR_CK * 0x1p-23)
#define BIAS26  0x04000000u             // 2^26 per-slot bias
#define GUARD_WORD 0x9C9C9C9Cu          // 4 x index 156 (bias-only guard row)

// ---------------------------------------------------------------------------
// K1: build packed active-index lists, PADDED to >=6 words with guard slots.
// ---------------------------------------------------------------------------
__global__ void __launch_bounds__(256) k_build_lists(
    const float* __restrict__ x,
    uint32_t* __restrict__ lists_m, uint32_t* __restrict__ cnt_m,
    uint32_t* __restrict__ lists_l, uint32_t* __restrict__ cnt_l)
{
  extern __shared__ float xl[];            // [156*156]
  const int n = blockIdx.x;
  const float* xn = x + n * (C_IN * T_SMP);
  for (int i = threadIdx.x; i < C_IN * T_SMP; i += 256) xl[i] = xn[i];
  __syncthreads();
  const int t = threadIdx.x;
  if (t < T_SMP) {
    { // main path
      uint32_t* Lp = lists_m + (n * T_SMP + t) * 40;
      uint32_t w = 0; int cnt = 0, nw = 0;
      for (int c = 0; c < C_IN; ++c) {
        if (xl[c * T_SMP + t] > 0.5f) {
          w |= ((uint32_t)c) << ((cnt & 3) * 8);
          ++cnt;
          if ((cnt & 3) == 0) { Lp[nw++] = w; w = 0; }
        }
      }
      if (cnt & 3) {
        for (int k = cnt & 3; k < 4; ++k) w |= 156u << (k * 8);
        Lp[nw++] = w;
      }
      cnt_m[n * T_SMP + t] = (uint32_t)nw;
      for (int k = nw; k < 6; ++k) Lp[k] = GUARD_WORD;
    }
    { // location path
      uint32_t* Lp = lists_l + (n * T_SMP + t) * 40;
      const int pc = PERM_C[t];
      uint32_t w = 0; int cnt = 0, nw = 0;
      for (int tau = 0; tau < T_SMP; ++tau) {
        if (xl[pc * T_SMP + tau] > 0.5f) {
          w |= ((uint32_t)tau) << ((cnt & 3) * 8);
          ++cnt;
          if ((cnt & 3) == 0) { Lp[nw++] = w; w = 0; }
        }
      }
      if (cnt & 3) {
        for (int k = cnt & 3; k < 4; ++k) w |= 156u << (k * 8);
        Lp[nw++] = w;
      }
      cnt_l[n * T_SMP + t] = (uint32_t)nw;
      for (int k = nw; k < 6; ++k) Lp[k] = GUARD_WORD;
    }
  }
}

// ---------------------------------------------------------------------------
// K2 v12: v11 numerics, 512-thread blocks for MAX occupancy.
// 8 waves/block = 8 batches sharing one 40.2KB wB table; 4 blocks/CU ->
// 32 waves/CU = 8 waves/SIMD (was 4). VGPR 28 <= 64 fits. Per-wave
// computation (u32-exact gather, f64 IIR, f32 pend) bit-identical to v11.
// Grid: (16 hc, 16 n-groups of 8, 2 path) = 512 blocks.
// ---------------------------------------------------------------------------
__global__ void __launch_bounds__(512, 8) k_layer1(
    const float* __restrict__ w_fc1, const float* __restrict__ w_loc1,
    const uint32_t* __restrict__ lists_m, const uint32_t* __restrict__ cnt_m,
    const uint32_t* __restrict__ lists_l, const uint32_t* __restrict__ cnt_l,
    uint64_t* __restrict__ s1m_m, uint64_t* __restrict__ s1m_l)
{
  extern __shared__ uint32_t wB[];         // [157][64]
  const int hc   = blockIdx.x;             // 0..15 (h chunk of 64)
  const int n0   = blockIdx.y * 8;
  const int path = blockIdx.z;
  const int tid  = threadIdx.x;
  const float* w = (path == 0) ? w_fc1 : w_loc1;
  const uint32_t* lists = (path == 0) ? lists_m : lists_l;
  const uint32_t* cnts  = (path == 0) ? cnt_m  : cnt_l;
  uint64_t* s1m = (path == 0) ? s1m_m : s1m_l;
  const int h0 = hc * 64;

  { // stage: thread tid owns h-row hp = tid&63, c-eighth e = tid>>6
    const int hp = tid & 63;
    const int e  = tid >> 6;                       // 0..7
    const int c0 = (e < 4) ? e * 20 : 80 + (e - 4) * 19;
    const int nc = (e < 4) ? 20 : 19;
    const float* wr = w + (size_t)(h0 + hp) * C_IN + c0;
    for (int k = 0; k < nc; ++k) {
      int q = __double2int_rn((double)wr[k] * 0x1p23);
      wB[(c0 + k) * 64 + hp] = (uint32_t)q + BIAS26;
    }
    if (tid < 64) wB[156 * 64 + tid] = BIAS26;  // guard row = bias only
  }
  __syncthreads();

  // wave-uniform scalars: SGPR residency for all list addressing
  const int wvu  = __builtin_amdgcn_readfirstlane(tid >> 6);  // 0..7
  const int lane = tid & 63;
  const int n    = n0 + wvu;
  const int rbase = n * T_SMP;

  // running scalar pointers (strength-reduced)
  const uint32_t* cp = cnts + rbase;                // cnt cursor
  const uint32_t* lp = lists + (size_t)rbase * 40;  // list cursor
  uint64_t* sp_out = s1m + (size_t)rbase * 16 + hc; // ballot cursor

  float pend[15];
  #pragma unroll
  for (int d = 0; d < 15; ++d) pend[d] = 0.0f;
  double e1 = 0.0, e2 = 0.0;

  // prefetch t=0 list (6 words) + count -- scalar loads
  int nw = (int)cp[0];
  uint4 pkA = *(const uint4*)lp;
  uint2 pkB = *(const uint2*)(lp + 4);

  for (int t = 0; t < T_SMP; ++t) {
    // unclamped prefetch of t+1 (garbage at t=155 never consumed; in-bounds)
    const int nw_n = (int)cp[1];
    const uint4 pkA_n = *(const uint4*)(lp + 40);
    const uint2 pkB_n = *(const uint2*)(lp + 44);

    uint32_t a0 = 0, a1 = 0, a2 = 0, a3 = 0;

#define DOWORD(PK) do {                                                      \
    uint32_t pk_ = (PK);                    /* SGPR: extracts on SALU */     \
    int c0_ = pk_ & 255, c1_ = (pk_ >> 8) & 255,                             \
        c2_ = (pk_ >> 16) & 255, c3_ = pk_ >> 24;                            \
    uint32_t F0 = wB[c0_ * 64 + lane];                                       \
    uint32_t F1 = wB[c1_ * 64 + lane];                                       \
    uint32_t F2 = wB[c2_ * 64 + lane];                                       \
    uint32_t F3 = wB[c3_ * 64 + lane];                                       \
    a0 += F0; a1 += F1; a2 += F2; a3 += F3;                                  \
  } while (0)

    // straight line: 20 slots (covers nact<=20, ~90% of t)
    DOWORD(pkA.x);
    DOWORD(pkA.y);
    DOWORD(pkA.z);
    DOWORD(pkA.w);
    DOWORD(pkB.x);
    uint32_t slots = 20;
    if (nw > 5) {                   // ~8.5%: word 6 already prefetched
      DOWORD(pkB.y);
      slots = 24;
      if (nw > 6) {                 // ~0.8%: memory tail
        for (int wi = 6; wi < nw; ++wi) DOWORD(lp[wi]);
        slots = (uint32_t)(4 * nw);
      }
    }
#undef DOWORD

    uint32_t sum = (a0 + a1) + (a2 + a3);
    int sw = (int)(sum - (slots << 26));       // exact mod-2^32 de-bias
    double upre = (double)sw * CKSCALE23;      // CK*2^-23 pre-folded
    e1 = IIR_A * e1 + upre;
    e2 = IIR_A * e2 + e1;
    float uf = (float)(e2 - e1);
    float um = uf + pend[0];
    bool sp = (um >= 10.0f);
    float s = sp ? 1.0f : 0.0f;
    #pragma unroll
    for (int d = 0; d < 14; ++d) pend[d] = fmaf(s, REFN_C[d], pend[d + 1]);
    pend[14] = s * REFN_C[14];
    uint64_t bal = __ballot(sp);
    if (lane == 0) *sp_out = bal;

    nw = nw_n; pkA = pkA_n; pkB = pkB_n;
    cp += 1; lp += 40; sp_out += 16;
  }
}

// ---------------------------------------------------------------------------
// K3 v7: layer-2 dense via bitmask. Per spike-bit: ONE ds_read_b128 (4 o)
// + ONE ds_read_b32 (5th o). ONE block per (n,path), 8 waves over t.
// ---------------------------------------------------------------------------
__global__ void __launch_bounds__(512, 1) k_layer2(
    const float* __restrict__ w_fc2, const float* __restrict__ w_loc2,
    const uint64_t* __restrict__ s1m_m, const uint64_t* __restrict__ s1m_l,
    float* __restrict__ u2_m, float* __restrict__ u2_l)
{
  extern __shared__ int4 w2a[];            // [1024*4] int4  (64KB)
  int* w2b = (int*)&w2a[H_HID * 4];        // [1024*4] int   (16KB)
  const int path = blockIdx.y;
  const int n = blockIdx.x;
  const float* w2 = (path == 0) ? w_fc2 : w_loc2;
  const uint64_t* s1m = (path == 0) ? s1m_m : s1m_l;
  float* u2 = (path == 0) ? u2_m : u2_l;
  for (int i = threadIdx.x; i < H_HID * 4; i += 512) {
    const int h = i >> 2, og = i & 3;
    int4 v;
    v.x = __double2int_rn((double)w2[(og +  0) * H_HID + h] * 0x1p31);
    v.y = __double2int_rn((double)w2[(og +  4) * H_HID + h] * 0x1p31);
    v.z = __double2int_rn((double)w2[(og +  8) * H_HID + h] * 0x1p31);
    v.w = __double2int_rn((double)w2[(og + 12) * H_HID + h] * 0x1p31);
    w2a[i] = v;
    w2b[i] = __double2int_rn((double)w2[(og + 16) * H_HID + h] * 0x1p31);
  }
  __syncthreads();
  const int wv   = threadIdx.x >> 6;
  const int lane = threadIdx.x & 63;
  const int hw = lane >> 2, og = lane & 3;

  for (int t = wv; t < T_SMP; t += 8) {
    const int id = n * T_SMP + t;
    uint64_t m = s1m[(size_t)id * 16 + hw];
    long long acc0 = 0, acc1 = 0, acc2 = 0, acc3 = 0, acc4 = 0;
    while (m) {
      int b = __builtin_ctzll(m);
      m &= m - 1;
      const int h = hw * 64 + b;
      const int4 va = w2a[h * 4 + og];
      const int  vb = w2b[h * 4 + og];
      acc0 += va.x;
      acc1 += va.y;
      acc2 += va.z;
      acc3 += va.w;
      acc4 += vb;
    }
    #pragma unroll
    for (int off = 4; off <= 32; off <<= 1) {
      acc0 += __shfl_xor(acc0, off);
      acc1 += __shfl_xor(acc1, off);
      acc2 += __shfl_xor(acc2, off);
      acc3 += __shfl_xor(acc3, off);
      acc4 += __shfl_xor(acc4, off);
    }
    if (lane < 4) {
      float* ub = u2 + (size_t)t * (N_BATCH * O_OUT) + n * O_OUT + og;
      ub[0]  = (float)((double)acc0 * 0x1p-31);
      ub[4]  = (float)((double)acc1 * 0x1p-31);
      ub[8]  = (float)((double)acc2 * 0x1p-31);
      ub[12] = (float)((double)acc3 * 0x1p-31);
      ub[16] = (float)((double)acc4 * 0x1p-31);
    }
  }
}

// ---------------------------------------------------------------------------
// K4: layer-2 psp (fp64 IIR) + spike scan, write concatenated output.
// ---------------------------------------------------------------------------
__global__ void __launch_bounds__(256) k_psp_spike_out(
    const float* __restrict__ u2_m, const float* __restrict__ u2_l,
    float* __restrict__ out)
{
  const int rid = blockIdx.x * 256 + threadIdx.x;   // 0..5119
  const int p = rid / (N_BATCH * O_OUT);
  const int r = rid % (N_BATCH * O_OUT);            // n*20+o
  const float* up = (p == 0) ? u2_m : u2_l;
  float* ob = out + (size_t)r * (2 * T_SMP) + p * T_SMP;
  float pend[15];
  #pragma unroll
  for (int d = 0; d < 15; ++d) pend[d] = 0.0f;
  double e1 = 0.0, e2 = 0.0;
  for (int t = 0; t < T_SMP; ++t) {
    double xv = (double)up[(size_t)t * (N_BATCH * O_OUT) + r];
    e1 = IIR_A * e1 + xv;
    e2 = IIR_A * e2 + e1;
    float uf = (float)(IIR_CK * (e2 - e1));
    float um = uf + pend[0];
    float s  = (um >= 10.0f) ? 1.0f : 0.0f;
    #pragma unroll
    for (int d = 0; d < 14; ++d) pend[d] = fmaf(s, REFN_C[d], pend[d + 1]);
    pend[14] = s * REFN_C[14];
    ob[t] = s;
  }
}

// ---------------------------------------------------------------------------
extern "C" void kernel_launch(void* const* d_in, const int* in_sizes, int n_in,
                              void* d_out, int out_size, void* d_ws, size_t ws_size,
                              hipStream_t stream) {
  const float* x      = (const float*)d_in[0];
  const float* w_fc1  = (const float*)d_in[1];
  const float* w_fc2  = (const float*)d_in[2];
  const float* w_loc1 = (const float*)d_in[3];
  const float* w_loc2 = (const float*)d_in[4];
  float* out = (float*)d_out;
  char* ws = (char*)d_ws;

  // workspace layout
  uint32_t* lists_m = (uint32_t*)(ws + 0);          //  3,194,880
  uint32_t* lists_l = (uint32_t*)(ws + 3194880);    //  3,194,880
  uint32_t* cnt_m   = (uint32_t*)(ws + 6389760);    //     79,872
  uint32_t* cnt_l   = (uint32_t*)(ws + 6469632);    //     79,872
  uint64_t* s1m_m   = (uint64_t*)(ws + 6549504);    //  2,555,904
  uint64_t* s1m_l   = (uint64_t*)(ws + 9105408);    //  2,555,904
  float*    u2_m    = (float*)   (ws + 11661312);   //  1,597,440
  float*    u2_l    = (float*)   (ws + 13258752);   //  1,597,440

  hipLaunchKernelGGL(k_build_lists, dim3(128), dim3(256),
                     C_IN * T_SMP * sizeof(float), stream,
                     x, lists_m, cnt_m, lists_l, cnt_l);
  hipLaunchKernelGGL(k_layer1, dim3(16, 16, 2), dim3(512),
                     157 * 64 * sizeof(uint32_t), stream,
                     w_fc1, w_loc1, lists_m, cnt_m, lists_l, cnt_l, s1m_m, s1m_l);
  hipLaunchKernelGGL(k_layer2, dim3(128, 2), dim3(512),
                     H_HID * 4 * sizeof(int4) + H_HID * 4 * sizeof(int), stream,
                     w_fc2, w_loc2, s1m_m, s1m_l, u2_m, u2_l);
  hipLaunchKernelGGL(k_psp_spike_out, dim3(20), dim3(256), 0, stream,
                     u2_m, u2_l, out);
}

// Round 13
// 299.724 us; speedup vs baseline: 1.0177x; 1.0177x over previous
//
#include <hip/hip_runtime.h>
#include <stdint.h>

#define N_BATCH 128
#define C_IN    156
#define T_SMP   156
#define H_HID   1024
#define O_OUT   20

// Baked permutation (from reference _top_down construction)
__constant__ int PERM_C[156] = {
  20,21,48,49,68,69,6,7,34,35,58,59,12,13,2,3,38,39,72,73,56,57,22,23,16,17,
  64,65,44,45,30,31,0,1,10,11,28,29,40,41,52,53,66,67,76,77,46,47,32,33,18,19,
  60,61,74,75,54,55,26,27,4,5,42,43,62,63,14,15,36,37,70,71,8,9,24,25,50,51,
  98,99,126,127,146,147,84,85,112,113,136,137,90,91,80,81,116,117,150,151,134,135,
  100,101,94,95,142,143,122,123,108,109,78,79,88,89,106,107,118,119,130,131,144,145,
  154,155,124,125,110,111,96,97,138,139,152,153,132,133,104,105,82,83,120,121,
  140,141,92,93,114,115,148,149,86,87,102,103,128,129
};

// ref_next[d] = REF_KERNEL[d+1] = -20*(d+1)*exp(-d), correctly-rounded fp32
__device__ __constant__ float REFN_C[15] = {
  -20.0f,
  -14.7151776468576930f,
  -8.1201169941967630f,
  -3.9829654694291155f,
  -1.8315638888734178f,
  -0.80855363989025606f,
  -0.34702530473329017f,
  -0.14590111448872258f,
  -0.060383273022452135f,
  -0.024681960817335913f,
  -0.0099879845477466679f,
  -0.0040084081896589585f,
  -0.0015974952118653345f,
  -0.00063348115597555236f,
  -0.00024945861573107036f
};

#define IIR_A   0.904837418035959573    // exp(-1/10)
#define IIR_CK  0.271828182845904524    // e/10
// CK * 2^-23 folded into the i32->f64 scale (IIR is linear)
#define CKSCALE23 (IIR_CK * 0x1p-23)
#define BIAS26  0x04000000u             // 2^26 per-slot bias
#define GUARD_WORD 0x9C9C9C9Cu          // 4 x index 156 (bias-only guard row)

// ---------------------------------------------------------------------------
// K1: build packed active-index lists, PADDED to >=6 words with guard slots.
// ---------------------------------------------------------------------------
__global__ void __launch_bounds__(256) k_build_lists(
    const float* __restrict__ x,
    uint32_t* __restrict__ lists_m, uint32_t* __restrict__ cnt_m,
    uint32_t* __restrict__ lists_l, uint32_t* __restrict__ cnt_l)
{
  extern __shared__ float xl[];            // [156*156]
  const int n = blockIdx.x;
  const float* xn = x + n * (C_IN * T_SMP);
  for (int i = threadIdx.x; i < C_IN * T_SMP; i += 256) xl[i] = xn[i];
  __syncthreads();
  const int t = threadIdx.x;
  if (t < T_SMP) {
    { // main path
      uint32_t* Lp = lists_m + (n * T_SMP + t) * 40;
      uint32_t w = 0; int cnt = 0, nw = 0;
      for (int c = 0; c < C_IN; ++c) {
        if (xl[c * T_SMP + t] > 0.5f) {
          w |= ((uint32_t)c) << ((cnt & 3) * 8);
          ++cnt;
          if ((cnt & 3) == 0) { Lp[nw++] = w; w = 0; }
        }
      }
      if (cnt & 3) {
        for (int k = cnt & 3; k < 4; ++k) w |= 156u << (k * 8);
        Lp[nw++] = w;
      }
      cnt_m[n * T_SMP + t] = (uint32_t)nw;
      for (int k = nw; k < 6; ++k) Lp[k] = GUARD_WORD;
    }
    { // location path
      uint32_t* Lp = lists_l + (n * T_SMP + t) * 40;
      const int pc = PERM_C[t];
      uint32_t w = 0; int cnt = 0, nw = 0;
      for (int tau = 0; tau < T_SMP; ++tau) {
        if (xl[pc * T_SMP + tau] > 0.5f) {
          w |= ((uint32_t)tau) << ((cnt & 3) * 8);
          ++cnt;
          if ((cnt & 3) == 0) { Lp[nw++] = w; w = 0; }
        }
      }
      if (cnt & 3) {
        for (int k = cnt & 3; k < 4; ++k) w |= 156u << (k * 8);
        Lp[nw++] = w;
      }
      cnt_l[n * T_SMP + t] = (uint32_t)nw;
      for (int k = nw; k < 6; ++k) Lp[k] = GUARD_WORD;
    }
  }
}

// ---------------------------------------------------------------------------
// K2 v13: v11 numerics + 1-deep software pipeline.
// Loop body: {scalar-load lists(t+2)} || {gather(t+1) from lists loaded last
// iter} || {IIR+spike(t) from last iter's gather}. gather(t+1) and IIR(t)
// are independent -> gather VALU fills the f64 IIR latency bubbles.
// List prefetch depth 2 covers scalar-load latency; clamped addressing keeps
// everything in-bounds (one discarded tail gather). u32-exact table/de-bias
// identical to v11 (absmax 0). 256 thr = 4 waves = 4 batches, 4 blocks/CU.
// ---------------------------------------------------------------------------
__global__ void __launch_bounds__(256, 4) k_layer1(
    const float* __restrict__ w_fc1, const float* __restrict__ w_loc1,
    const uint32_t* __restrict__ lists_m, const uint32_t* __restrict__ cnt_m,
    const uint32_t* __restrict__ lists_l, const uint32_t* __restrict__ cnt_l,
    uint64_t* __restrict__ s1m_m, uint64_t* __restrict__ s1m_l)
{
  extern __shared__ uint32_t wB[];         // [157][64]
  const int hc   = blockIdx.x;             // 0..15 (h chunk of 64)
  const int n0   = blockIdx.y * 4;
  const int path = blockIdx.z;
  const int tid  = threadIdx.x;
  const float* w = (path == 0) ? w_fc1 : w_loc1;
  const uint32_t* lists = (path == 0) ? lists_m : lists_l;
  const uint32_t* cnts  = (path == 0) ? cnt_m  : cnt_l;
  uint64_t* s1m = (path == 0) ? s1m_m : s1m_l;
  const int h0 = hc * 64;

  { // stage: thread tid owns h-row hp = tid&63, c-quarter = tid>>6 (39 c each)
    const int hp = tid & 63;
    const int c0 = (tid >> 6) * 39;
    const float* wr = w + (size_t)(h0 + hp) * C_IN + c0;
    #pragma unroll
    for (int k = 0; k < 39; ++k) {
      int q = __double2int_rn((double)wr[k] * 0x1p23);
      wB[(c0 + k) * 64 + hp] = (uint32_t)q + BIAS26;
    }
    if (tid < 64) wB[156 * 64 + tid] = BIAS26;  // guard row = bias only
  }
  __syncthreads();

  // wave-uniform scalars: SGPR residency for all list addressing
  const int wvu  = __builtin_amdgcn_readfirstlane(tid >> 6);
  const int lane = tid & 63;
  const int n    = n0 + wvu;
  const int rbase = n * T_SMP;

  // running scalar pointers (strength-reduced)
  const uint32_t* cp = cnts + rbase;                // cnt cursor
  const uint32_t* lp = lists + (size_t)rbase * 40;  // list cursor
  uint64_t* sp_out = s1m + (size_t)rbase * 16 + hc; // ballot cursor

  float pend[15];
  #pragma unroll
  for (int d = 0; d < 15; ++d) pend[d] = 0.0f;
  double e1 = 0.0, e2 = 0.0;

#define DOWORD(PK) do {                                                      \
    uint32_t pk_ = (PK);                    /* SGPR: extracts on SALU */     \
    int c0_ = pk_ & 255, c1_ = (pk_ >> 8) & 255,                             \
        c2_ = (pk_ >> 16) & 255, c3_ = pk_ >> 24;                            \
    uint32_t F0 = wB[c0_ * 64 + lane];                                       \
    uint32_t F1 = wB[c1_ * 64 + lane];                                       \
    uint32_t F2 = wB[c2_ * 64 + lane];                                       \
    uint32_t F3 = wB[c3_ * 64 + lane];                                       \
    a0 += F0; a1 += F1; a2 += F2; a3 += F3;                                  \
  } while (0)

  // --- prologue: lists(0), gather(0), lists(1) ---
  int nwc = (int)cp[0];
  uint4 Ac = *(const uint4*)lp;
  uint2 Bc = *(const uint2*)(lp + 4);
  uint32_t ga0, ga1, ga2, ga3, gslots;
  {
    uint32_t a0 = 0, a1 = 0, a2 = 0, a3 = 0;
    DOWORD(Ac.x); DOWORD(Ac.y); DOWORD(Ac.z); DOWORD(Ac.w); DOWORD(Bc.x);
    uint32_t slots = 20;
    if (nwc > 5) {
      DOWORD(Bc.y);
      slots = 24;
      if (nwc > 6) {
        for (int wi = 6; wi < nwc; ++wi) DOWORD(lp[wi]);
        slots = (uint32_t)(4 * nwc);
      }
    }
    ga0 = a0; ga1 = a1; ga2 = a2; ga3 = a3; gslots = slots;
  }
  int nw1 = (int)cp[1];
  uint4 A1 = *(const uint4*)(lp + 40);
  uint2 B1 = *(const uint2*)(lp + 44);

  for (int t = 0; t < T_SMP; ++t) {
    // scalar-load lists(t+2), clamped (garbage iterations' results discarded)
    const int adv = (t < T_SMP - 2) ? 2 : 0;
    const int nw2 = (int)cp[adv];
    const uint4 A2 = *(const uint4*)(lp + adv * 40);
    const uint2 B2 = *(const uint2*)(lp + adv * 40 + 4);

    // gather(t+1) from lists loaded last iteration (resident in SGPRs)
    uint32_t na0, na1, na2, na3, nslots;
    {
      uint32_t a0 = 0, a1 = 0, a2 = 0, a3 = 0;
      DOWORD(A1.x); DOWORD(A1.y); DOWORD(A1.z); DOWORD(A1.w); DOWORD(B1.x);
      uint32_t slots = 20;
      if (nw1 > 5) {
        DOWORD(B1.y);
        slots = 24;
        if (nw1 > 6) {
          const uint32_t* lt = lp + 40;   // list of t+1
          for (int wi = 6; wi < nw1; ++wi) DOWORD(lt[wi]);
          slots = (uint32_t)(4 * nw1);
        }
      }
      na0 = a0; na1 = a1; na2 = a2; na3 = a3; nslots = slots;
    }

    // IIR + spike for t from last iteration's gather (independent of above)
    uint32_t sum = (ga0 + ga1) + (ga2 + ga3);
    int sw = (int)(sum - (gslots << 26));      // exact mod-2^32 de-bias
    double upre = (double)sw * CKSCALE23;      // CK*2^-23 pre-folded
    e1 = IIR_A * e1 + upre;
    e2 = IIR_A * e2 + e1;
    float uf = (float)(e2 - e1);
    float um = uf + pend[0];
    bool sp = (um >= 10.0f);
    float s = sp ? 1.0f : 0.0f;
    #pragma unroll
    for (int d = 0; d < 14; ++d) pend[d] = fmaf(s, REFN_C[d], pend[d + 1]);
    pend[14] = s * REFN_C[14];
    uint64_t bal = __ballot(sp);
    if (lane == 0) *sp_out = bal;

    // rotate pipeline registers
    ga0 = na0; ga1 = na1; ga2 = na2; ga3 = na3; gslots = nslots;
    nw1 = nw2; A1 = A2; B1 = B2;
    cp += 1; lp += 40; sp_out += 16;
  }
#undef DOWORD
}

// ---------------------------------------------------------------------------
// K3 v7: layer-2 dense via bitmask. Per spike-bit: ONE ds_read_b128 (4 o)
// + ONE ds_read_b32 (5th o). ONE block per (n,path), 8 waves over t.
// ---------------------------------------------------------------------------
__global__ void __launch_bounds__(512, 1) k_layer2(
    const float* __restrict__ w_fc2, const float* __restrict__ w_loc2,
    const uint64_t* __restrict__ s1m_m, const uint64_t* __restrict__ s1m_l,
    float* __restrict__ u2_m, float* __restrict__ u2_l)
{
  extern __shared__ int4 w2a[];            // [1024*4] int4  (64KB)
  int* w2b = (int*)&w2a[H_HID * 4];        // [1024*4] int   (16KB)
  const int path = blockIdx.y;
  const int n = blockIdx.x;
  const float* w2 = (path == 0) ? w_fc2 : w_loc2;
  const uint64_t* s1m = (path == 0) ? s1m_m : s1m_l;
  float* u2 = (path == 0) ? u2_m : u2_l;
  for (int i = threadIdx.x; i < H_HID * 4; i += 512) {
    const int h = i >> 2, og = i & 3;
    int4 v;
    v.x = __double2int_rn((double)w2[(og +  0) * H_HID + h] * 0x1p31);
    v.y = __double2int_rn((double)w2[(og +  4) * H_HID + h] * 0x1p31);
    v.z = __double2int_rn((double)w2[(og +  8) * H_HID + h] * 0x1p31);
    v.w = __double2int_rn((double)w2[(og + 12) * H_HID + h] * 0x1p31);
    w2a[i] = v;
    w2b[i] = __double2int_rn((double)w2[(og + 16) * H_HID + h] * 0x1p31);
  }
  __syncthreads();
  const int wv   = threadIdx.x >> 6;
  const int lane = threadIdx.x & 63;
  const int hw = lane >> 2, og = lane & 3;

  for (int t = wv; t < T_SMP; t += 8) {
    const int id = n * T_SMP + t;
    uint64_t m = s1m[(size_t)id * 16 + hw];
    long long acc0 = 0, acc1 = 0, acc2 = 0, acc3 = 0, acc4 = 0;
    while (m) {
      int b = __builtin_ctzll(m);
      m &= m - 1;
      const int h = hw * 64 + b;
      const int4 va = w2a[h * 4 + og];
      const int  vb = w2b[h * 4 + og];
      acc0 += va.x;
      acc1 += va.y;
      acc2 += va.z;
      acc3 += va.w;
      acc4 += vb;
    }
    #pragma unroll
    for (int off = 4; off <= 32; off <<= 1) {
      acc0 += __shfl_xor(acc0, off);
      acc1 += __shfl_xor(acc1, off);
      acc2 += __shfl_xor(acc2, off);
      acc3 += __shfl_xor(acc3, off);
      acc4 += __shfl_xor(acc4, off);
    }
    if (lane < 4) {
      float* ub = u2 + (size_t)t * (N_BATCH * O_OUT) + n * O_OUT + og;
      ub[0]  = (float)((double)acc0 * 0x1p-31);
      ub[4]  = (float)((double)acc1 * 0x1p-31);
      ub[8]  = (float)((double)acc2 * 0x1p-31);
      ub[12] = (float)((double)acc3 * 0x1p-31);
      ub[16] = (float)((double)acc4 * 0x1p-31);
    }
  }
}

// ---------------------------------------------------------------------------
// K4: layer-2 psp (fp64 IIR) + spike scan, write concatenated output.
// ---------------------------------------------------------------------------
__global__ void __launch_bounds__(256) k_psp_spike_out(
    const float* __restrict__ u2_m, const float* __restrict__ u2_l,
    float* __restrict__ out)
{
  const int rid = blockIdx.x * 256 + threadIdx.x;   // 0..5119
  const int p = rid / (N_BATCH * O_OUT);
  const int r = rid % (N_BATCH * O_OUT);            // n*20+o
  const float* up = (p == 0) ? u2_m : u2_l;
  float* ob = out + (size_t)r * (2 * T_SMP) + p * T_SMP;
  float pend[15];
  #pragma unroll
  for (int d = 0; d < 15; ++d) pend[d] = 0.0f;
  double e1 = 0.0, e2 = 0.0;
  for (int t = 0; t < T_SMP; ++t) {
    double xv = (double)up[(size_t)t * (N_BATCH * O_OUT) + r];
    e1 = IIR_A * e1 + xv;
    e2 = IIR_A * e2 + e1;
    float uf = (float)(IIR_CK * (e2 - e1));
    float um = uf + pend[0];
    float s  = (um >= 10.0f) ? 1.0f : 0.0f;
    #pragma unroll
    for (int d = 0; d < 14; ++d) pend[d] = fmaf(s, REFN_C[d], pend[d + 1]);
    pend[14] = s * REFN_C[14];
    ob[t] = s;
  }
}

// ---------------------------------------------------------------------------
extern "C" void kernel_launch(void* const* d_in, const int* in_sizes, int n_in,
                              void* d_out, int out_size, void* d_ws, size_t ws_size,
                              hipStream_t stream) {
  const float* x      = (const float*)d_in[0];
  const float* w_fc1  = (const float*)d_in[1];
  const float* w_fc2  = (const float*)d_in[2];
  const float* w_loc1 = (const float*)d_in[3];
  const float* w_loc2 = (const float*)d_in[4];
  float* out = (float*)d_out;
  char* ws = (char*)d_ws;

  // workspace layout
  uint32_t* lists_m = (uint32_t*)(ws + 0);          //  3,194,880
  uint32_t* lists_l = (uint32_t*)(ws + 3194880);    //  3,194,880
  uint32_t* cnt_m   = (uint32_t*)(ws + 6389760);    //     79,872
  uint32_t* cnt_l   = (uint32_t*)(ws + 6469632);    //     79,872
  uint64_t* s1m_m   = (uint64_t*)(ws + 6549504);    //  2,555,904
  uint64_t* s1m_l   = (uint64_t*)(ws + 9105408);    //  2,555,904
  float*    u2_m    = (float*)   (ws + 11661312);   //  1,597,440
  float*    u2_l    = (float*)   (ws + 13258752);   //  1,597,440

  hipLaunchKernelGGL(k_build_lists, dim3(128), dim3(256),
                     C_IN * T_SMP * sizeof(float), stream,
                     x, lists_m, cnt_m, lists_l, cnt_l);
  hipLaunchKernelGGL(k_layer1, dim3(16, 32, 2), dim3(256),
                     157 * 64 * sizeof(uint32_t), stream,
                     w_fc1, w_loc1, lists_m, cnt_m, lists_l, cnt_l, s1m_m, s1m_l);
  hipLaunchKernelGGL(k_layer2, dim3(128, 2), dim3(512),
                     H_HID * 4 * sizeof(int4) + H_HID * 4 * sizeof(int), stream,
                     w_fc2, w_loc2, s1m_m, s1m_l, u2_m, u2_l);
  hipLaunchKernelGGL(k_psp_spike_out, dim3(20), dim3(256), 0, stream,
                     u2_m, u2_l, out);
}

// Round 14
// 295.146 us; speedup vs baseline: 1.0335x; 1.0155x over previous
//
#include <hip/hip_runtime.h>
#include <stdint.h>

#define N_BATCH 128
#define C_IN    156
#define T_SMP   156
#define H_HID   1024
#define O_OUT   20

// Baked permutation (from reference _top_down construction)
__constant__ int PERM_C[156] = {
  20,21,48,49,68,69,6,7,34,35,58,59,12,13,2,3,38,39,72,73,56,57,22,23,16,17,
  64,65,44,45,30,31,0,1,10,11,28,29,40,41,52,53,66,67,76,77,46,47,32,33,18,19,
  60,61,74,75,54,55,26,27,4,5,42,43,62,63,14,15,36,37,70,71,8,9,24,25,50,51,
  98,99,126,127,146,147,84,85,112,113,136,137,90,91,80,81,116,117,150,151,134,135,
  100,101,94,95,142,143,122,123,108,109,78,79,88,89,106,107,118,119,130,131,144,145,
  154,155,124,125,110,111,96,97,138,139,152,153,132,133,104,105,82,83,120,121,
  140,141,92,93,114,115,148,149,86,87,102,103,128,129
};

// ref_next[d] = REF_KERNEL[d+1] = -20*(d+1)*exp(-d), correctly-rounded fp32
__device__ __constant__ float REFN_C[15] = {
  -20.0f,
  -14.7151776468576930f,
  -8.1201169941967630f,
  -3.9829654694291155f,
  -1.8315638888734178f,
  -0.80855363989025606f,
  -0.34702530473329017f,
  -0.14590111448872258f,
  -0.060383273022452135f,
  -0.024681960817335913f,
  -0.0099879845477466679f,
  -0.0040084081896589585f,
  -0.0015974952118653345f,
  -0.00063348115597555236f,
  -0.00024945861573107036f
};

#define IIR_A   0.904837418035959573    // exp(-1/10)
#define IIR_CK  0.271828182845904524    // e/10
// CK * 2^-23 folded into the i32->f64 scale (IIR is linear)
#define CKSCALE23 (IIR_CK * 0x1p-23)
#define BIAS26  0x04000000u             // 2^26 per-slot bias
#define GUARD_WORD 0x9C9C9C9Cu          // 4 x index 156 (bias-only guard row)

// ---------------------------------------------------------------------------
// K1: build packed active-index lists, PADDED to >=6 words with guard slots.
// ---------------------------------------------------------------------------
__global__ void __launch_bounds__(256) k_build_lists(
    const float* __restrict__ x,
    uint32_t* __restrict__ lists_m, uint32_t* __restrict__ cnt_m,
    uint32_t* __restrict__ lists_l, uint32_t* __restrict__ cnt_l)
{
  extern __shared__ float xl[];            // [156*156]
  const int n = blockIdx.x;
  const float* xn = x + n * (C_IN * T_SMP);
  for (int i = threadIdx.x; i < C_IN * T_SMP; i += 256) xl[i] = xn[i];
  __syncthreads();
  const int t = threadIdx.x;
  if (t < T_SMP) {
    { // main path
      uint32_t* Lp = lists_m + (n * T_SMP + t) * 40;
      uint32_t w = 0; int cnt = 0, nw = 0;
      for (int c = 0; c < C_IN; ++c) {
        if (xl[c * T_SMP + t] > 0.5f) {
          w |= ((uint32_t)c) << ((cnt & 3) * 8);
          ++cnt;
          if ((cnt & 3) == 0) { Lp[nw++] = w; w = 0; }
        }
      }
      if (cnt & 3) {
        for (int k = cnt & 3; k < 4; ++k) w |= 156u << (k * 8);
        Lp[nw++] = w;
      }
      cnt_m[n * T_SMP + t] = (uint32_t)nw;
      for (int k = nw; k < 6; ++k) Lp[k] = GUARD_WORD;
    }
    { // location path
      uint32_t* Lp = lists_l + (n * T_SMP + t) * 40;
      const int pc = PERM_C[t];
      uint32_t w = 0; int cnt = 0, nw = 0;
      for (int tau = 0; tau < T_SMP; ++tau) {
        if (xl[pc * T_SMP + tau] > 0.5f) {
          w |= ((uint32_t)tau) << ((cnt & 3) * 8);
          ++cnt;
          if ((cnt & 3) == 0) { Lp[nw++] = w; w = 0; }
        }
      }
      if (cnt & 3) {
        for (int k = cnt & 3; k < 4; ++k) w |= 156u << (k * 8);
        Lp[nw++] = w;
      }
      cnt_l[n * T_SMP + t] = (uint32_t)nw;
      for (int k = nw; k < 6; ++k) Lp[k] = GUARD_WORD;
    }
  }
}

// ---------------------------------------------------------------------------
// K2 v14: v11 numerics + BATCHED LDS loads.
// All 20 straight-line ds_read_b32 issued into 20 named locals BEFORE any
// consumer -> compiler can keep them all in flight (one lgkmcnt wait), vs
// v11's read+add interleave that forced a wait every 4 reads (VGPR=28).
// Tree-sum of u32 values is order-independent and EXACT -> bitwise-identical
// results to v11 (absmax 0). 256 thr = 4 waves = 4 batches, 4 blocks/CU.
// ---------------------------------------------------------------------------
__global__ void __launch_bounds__(256, 4) k_layer1(
    const float* __restrict__ w_fc1, const float* __restrict__ w_loc1,
    const uint32_t* __restrict__ lists_m, const uint32_t* __restrict__ cnt_m,
    const uint32_t* __restrict__ lists_l, const uint32_t* __restrict__ cnt_l,
    uint64_t* __restrict__ s1m_m, uint64_t* __restrict__ s1m_l)
{
  extern __shared__ uint32_t wB[];         // [157][64]
  const int hc   = blockIdx.x;             // 0..15 (h chunk of 64)
  const int n0   = blockIdx.y * 4;
  const int path = blockIdx.z;
  const int tid  = threadIdx.x;
  const float* w = (path == 0) ? w_fc1 : w_loc1;
  const uint32_t* lists = (path == 0) ? lists_m : lists_l;
  const uint32_t* cnts  = (path == 0) ? cnt_m  : cnt_l;
  uint64_t* s1m = (path == 0) ? s1m_m : s1m_l;
  const int h0 = hc * 64;

  { // stage: thread tid owns h-row hp = tid&63, c-quarter = tid>>6 (39 c each)
    const int hp = tid & 63;
    const int c0 = (tid >> 6) * 39;
    const float* wr = w + (size_t)(h0 + hp) * C_IN + c0;
    #pragma unroll
    for (int k = 0; k < 39; ++k) {
      int q = __double2int_rn((double)wr[k] * 0x1p23);
      wB[(c0 + k) * 64 + hp] = (uint32_t)q + BIAS26;
    }
    if (tid < 64) wB[156 * 64 + tid] = BIAS26;  // guard row = bias only
  }
  __syncthreads();

  // wave-uniform scalars: SGPR residency for all list addressing
  const int wvu  = __builtin_amdgcn_readfirstlane(tid >> 6);
  const int lane = tid & 63;
  const int n    = n0 + wvu;
  const int rbase = n * T_SMP;

  // running scalar pointers (strength-reduced)
  const uint32_t* cp = cnts + rbase;                // cnt cursor
  const uint32_t* lp = lists + (size_t)rbase * 40;  // list cursor
  uint64_t* sp_out = s1m + (size_t)rbase * 16 + hc; // ballot cursor

  float pend[15];
  #pragma unroll
  for (int d = 0; d < 15; ++d) pend[d] = 0.0f;
  double e1 = 0.0, e2 = 0.0;

  // prefetch t=0 list (6 words) + count -- scalar loads
  int nw = (int)cp[0];
  uint4 pkA = *(const uint4*)lp;
  uint2 pkB = *(const uint2*)(lp + 4);

#define LOADW(PK, Fa, Fb, Fc, Fd) do {                                       \
    uint32_t pk_ = (PK);                    /* SGPR: extracts on SALU */     \
    (Fa) = wB[(pk_ & 255) * 64 + lane];                                      \
    (Fb) = wB[((pk_ >> 8) & 255) * 64 + lane];                               \
    (Fc) = wB[((pk_ >> 16) & 255) * 64 + lane];                              \
    (Fd) = wB[(pk_ >> 24) * 64 + lane];                                      \
  } while (0)

  for (int t = 0; t < T_SMP; ++t) {
    // unclamped prefetch of t+1 (garbage at t=155 never consumed; in-bounds)
    const int nw_n = (int)cp[1];
    const uint4 pkA_n = *(const uint4*)(lp + 40);
    const uint2 pkB_n = *(const uint2*)(lp + 44);

    // phase 1: issue ALL 20 loads (independent -> stay in flight together)
    uint32_t f0,f1,f2,f3,f4,f5,f6,f7,f8,f9,
             f10,f11,f12,f13,f14,f15,f16,f17,f18,f19;
    LOADW(pkA.x, f0,  f1,  f2,  f3);
    LOADW(pkA.y, f4,  f5,  f6,  f7);
    LOADW(pkA.z, f8,  f9,  f10, f11);
    LOADW(pkA.w, f12, f13, f14, f15);
    LOADW(pkB.x, f16, f17, f18, f19);

    // phase 2: exact tree-sum (u32, order-independent)
    uint32_t s0 = f0 + f1,  s1 = f2 + f3,  s2 = f4 + f5,  s3 = f6 + f7;
    uint32_t s4 = f8 + f9,  s5 = f10 + f11, s6 = f12 + f13, s7 = f14 + f15;
    uint32_t s8 = f16 + f17, s9 = f18 + f19;
    uint32_t sum = (((s0 + s1) + (s2 + s3)) + ((s4 + s5) + (s6 + s7)))
                 + (s8 + s9);
    uint32_t slots = 20;
    if (nw > 5) {                   // ~8.5%: word 6 already prefetched
      uint32_t g0, g1, g2, g3;
      LOADW(pkB.y, g0, g1, g2, g3);
      sum += (g0 + g1) + (g2 + g3);
      slots = 24;
      if (nw > 6) {                 // ~0.8%: memory tail
        for (int wi = 6; wi < nw; ++wi) {
          uint32_t h0_, h1_, h2_, h3_;
          LOADW(lp[wi], h0_, h1_, h2_, h3_);
          sum += (h0_ + h1_) + (h2_ + h3_);
        }
        slots = (uint32_t)(4 * nw);
      }
    }

    int sw = (int)(sum - (slots << 26));       // exact mod-2^32 de-bias
    double upre = (double)sw * CKSCALE23;      // CK*2^-23 pre-folded
    e1 = IIR_A * e1 + upre;
    e2 = IIR_A * e2 + e1;
    float uf = (float)(e2 - e1);
    float um = uf + pend[0];
    bool sp = (um >= 10.0f);
    float s = sp ? 1.0f : 0.0f;
    #pragma unroll
    for (int d = 0; d < 14; ++d) pend[d] = fmaf(s, REFN_C[d], pend[d + 1]);
    pend[14] = s * REFN_C[14];
    uint64_t bal = __ballot(sp);
    if (lane == 0) *sp_out = bal;

    nw = nw_n; pkA = pkA_n; pkB = pkB_n;
    cp += 1; lp += 40; sp_out += 16;
  }
#undef LOADW
}

// ---------------------------------------------------------------------------
// K3 v7: layer-2 dense via bitmask. Per spike-bit: ONE ds_read_b128 (4 o)
// + ONE ds_read_b32 (5th o). ONE block per (n,path), 8 waves over t.
// ---------------------------------------------------------------------------
__global__ void __launch_bounds__(512, 1) k_layer2(
    const float* __restrict__ w_fc2, const float* __restrict__ w_loc2,
    const uint64_t* __restrict__ s1m_m, const uint64_t* __restrict__ s1m_l,
    float* __restrict__ u2_m, float* __restrict__ u2_l)
{
  extern __shared__ int4 w2a[];            // [1024*4] int4  (64KB)
  int* w2b = (int*)&w2a[H_HID * 4];        // [1024*4] int   (16KB)
  const int path = blockIdx.y;
  const int n = blockIdx.x;
  const float* w2 = (path == 0) ? w_fc2 : w_loc2;
  const uint64_t* s1m = (path == 0) ? s1m_m : s1m_l;
  float* u2 = (path == 0) ? u2_m : u2_l;
  for (int i = threadIdx.x; i < H_HID * 4; i += 512) {
    const int h = i >> 2, og = i & 3;
    int4 v;
    v.x = __double2int_rn((double)w2[(og +  0) * H_HID + h] * 0x1p31);
    v.y = __double2int_rn((double)w2[(og +  4) * H_HID + h] * 0x1p31);
    v.z = __double2int_rn((double)w2[(og +  8) * H_HID + h] * 0x1p31);
    v.w = __double2int_rn((double)w2[(og + 12) * H_HID + h] * 0x1p31);
    w2a[i] = v;
    w2b[i] = __double2int_rn((double)w2[(og + 16) * H_HID + h] * 0x1p31);
  }
  __syncthreads();
  const int wv   = threadIdx.x >> 6;
  const int lane = threadIdx.x & 63;
  const int hw = lane >> 2, og = lane & 3;

  for (int t = wv; t < T_SMP; t += 8) {
    const int id = n * T_SMP + t;
    uint64_t m = s1m[(size_t)id * 16 + hw];
    long long acc0 = 0, acc1 = 0, acc2 = 0, acc3 = 0, acc4 = 0;
    while (m) {
      int b = __builtin_ctzll(m);
      m &= m - 1;
      const int h = hw * 64 + b;
      const int4 va = w2a[h * 4 + og];
      const int  vb = w2b[h * 4 + og];
      acc0 += va.x;
      acc1 += va.y;
      acc2 += va.z;
      acc3 += va.w;
      acc4 += vb;
    }
    #pragma unroll
    for (int off = 4; off <= 32; off <<= 1) {
      acc0 += __shfl_xor(acc0, off);
      acc1 += __shfl_xor(acc1, off);
      acc2 += __shfl_xor(acc2, off);
      acc3 += __shfl_xor(acc3, off);
      acc4 += __shfl_xor(acc4, off);
    }
    if (lane < 4) {
      float* ub = u2 + (size_t)t * (N_BATCH * O_OUT) + n * O_OUT + og;
      ub[0]  = (float)((double)acc0 * 0x1p-31);
      ub[4]  = (float)((double)acc1 * 0x1p-31);
      ub[8]  = (float)((double)acc2 * 0x1p-31);
      ub[12] = (float)((double)acc3 * 0x1p-31);
      ub[16] = (float)((double)acc4 * 0x1p-31);
    }
  }
}

// ---------------------------------------------------------------------------
// K4: layer-2 psp (fp64 IIR) + spike scan, write concatenated output.
// ---------------------------------------------------------------------------
__global__ void __launch_bounds__(256) k_psp_spike_out(
    const float* __restrict__ u2_m, const float* __restrict__ u2_l,
    float* __restrict__ out)
{
  const int rid = blockIdx.x * 256 + threadIdx.x;   // 0..5119
  const int p = rid / (N_BATCH * O_OUT);
  const int r = rid % (N_BATCH * O_OUT);            // n*20+o
  const float* up = (p == 0) ? u2_m : u2_l;
  float* ob = out + (size_t)r * (2 * T_SMP) + p * T_SMP;
  float pend[15];
  #pragma unroll
  for (int d = 0; d < 15; ++d) pend[d] = 0.0f;
  double e1 = 0.0, e2 = 0.0;
  for (int t = 0; t < T_SMP; ++t) {
    double xv = (double)up[(size_t)t * (N_BATCH * O_OUT) + r];
    e1 = IIR_A * e1 + xv;
    e2 = IIR_A * e2 + e1;
    float uf = (float)(IIR_CK * (e2 - e1));
    float um = uf + pend[0];
    float s  = (um >= 10.0f) ? 1.0f : 0.0f;
    #pragma unroll
    for (int d = 0; d < 14; ++d) pend[d] = fmaf(s, REFN_C[d], pend[d + 1]);
    pend[14] = s * REFN_C[14];
    ob[t] = s;
  }
}

// ---------------------------------------------------------------------------
extern "C" void kernel_launch(void* const* d_in, const int* in_sizes, int n_in,
                              void* d_out, int out_size, void* d_ws, size_t ws_size,
                              hipStream_t stream) {
  const float* x      = (const float*)d_in[0];
  const float* w_fc1  = (const float*)d_in[1];
  const float* w_fc2  = (const float*)d_in[2];
  const float* w_loc1 = (const float*)d_in[3];
  const float* w_loc2 = (const float*)d_in[4];
  float* out = (float*)d_out;
  char* ws = (char*)d_ws;

  // workspace layout
  uint32_t* lists_m = (uint32_t*)(ws + 0);          //  3,194,880
  uint32_t* lists_l = (uint32_t*)(ws + 3194880);    //  3,194,880
  uint32_t* cnt_m   = (uint32_t*)(ws + 6389760);    //     79,872
  uint32_t* cnt_l   = (uint32_t*)(ws + 6469632);    //     79,872
  uint64_t* s1m_m   = (uint64_t*)(ws + 6549504);    //  2,555,904
  uint64_t* s1m_l   = (uint64_t*)(ws + 9105408);    //  2,555,904
  float*    u2_m    = (float*)   (ws + 11661312);   //  1,597,440
  float*    u2_l    = (float*)   (ws + 13258752);   //  1,597,440

  hipLaunchKernelGGL(k_build_lists, dim3(128), dim3(256),
                     C_IN * T_SMP * sizeof(float), stream,
                     x, lists_m, cnt_m, lists_l, cnt_l);
  hipLaunchKernelGGL(k_layer1, dim3(16, 32, 2), dim3(256),
                     157 * 64 * sizeof(uint32_t), stream,
                     w_fc1, w_loc1, lists_m, cnt_m, lists_l, cnt_l, s1m_m, s1m_l);
  hipLaunchKernelGGL(k_layer2, dim3(128, 2), dim3(512),
                     H_HID * 4 * sizeof(int4) + H_HID * 4 * sizeof(int), stream,
                     w_fc2, w_loc2, s1m_m, s1m_l, u2_m, u2_l);
  hipLaunchKernelGGL(k_psp_spike_out, dim3(20), dim3(256), 0, stream,
                     u2_m, u2_l, out);
}